// Round 1
// baseline (416.445 us; speedup 1.0000x reference)
//
#include <hip/hip_runtime.h>
#include <stdint.h>

#define NN 50000
#define NPAD 50048   // padded row count so 128-row GEMM tiles never read OOB
#define NE 800000
#define DIM 256

typedef __attribute__((ext_vector_type(8))) short short8;
typedef __attribute__((ext_vector_type(4))) unsigned short ushort4v;
typedef __attribute__((ext_vector_type(8))) unsigned short ushort8v;
typedef __attribute__((ext_vector_type(4))) float floatx4;

__device__ __forceinline__ uint16_t f2bf(float f) {
  union { float f; uint32_t u; } v; v.f = f;
  uint32_t r = v.u + 0x7fffu + ((v.u >> 16) & 1u);
  return (uint16_t)(r >> 16);
}
__device__ __forceinline__ float bf2f(uint16_t h) {
  union { uint32_t u; float f; } v; v.u = ((uint32_t)h) << 16;
  return v.f;
}

// async global->LDS, 16B per lane; dest = wave-uniform base + lane*16
__device__ __forceinline__ void stage16(const uint16_t* gp, short* lbase, int lane) {
#if __has_builtin(__builtin_amdgcn_global_load_lds)
  __builtin_amdgcn_global_load_lds((__attribute__((address_space(1))) void*)gp,
                                   (__attribute__((address_space(3))) void*)lbase,
                                   16, 0, 0);
#else
  *(ushort8v*)((uint16_t*)lbase + lane * 8) = *(const ushort8v*)gp;
#endif
}

// ---------------- CSR build ----------------
__global__ __launch_bounds__(256) void k_zero(int* __restrict__ p, int n) {
  int i = blockIdx.x * 256 + threadIdx.x;
  if (i < n) p[i] = 0;
}

__global__ __launch_bounds__(256) void k_hist(const int* __restrict__ dst,
                                              int* __restrict__ hist) {
  int e = blockIdx.x * 256 + threadIdx.x;
  if (e < NE) atomicAdd(&hist[dst[e]], 1);
}

__global__ __launch_bounds__(256) void k_scan1(const int* __restrict__ hist,
                                               int* __restrict__ rowptr,
                                               int* __restrict__ bsums) {
  __shared__ int s[256];
  int i = blockIdx.x * 256 + threadIdx.x;
  int v = (i < NN) ? hist[i] : 0;
  s[threadIdx.x] = v;
  __syncthreads();
  for (int off = 1; off < 256; off <<= 1) {
    int t = (threadIdx.x >= off) ? s[threadIdx.x - off] : 0;
    __syncthreads();
    s[threadIdx.x] += t;
    __syncthreads();
  }
  if (i < NN) rowptr[i] = s[threadIdx.x] - v;  // exclusive (local)
  if (threadIdx.x == 255) bsums[blockIdx.x] = s[255];
}

__global__ __launch_bounds__(256) void k_scan2(int* __restrict__ bsums,
                                               int* __restrict__ rowptr, int nb) {
  __shared__ int s[256];
  int v = (threadIdx.x < nb) ? bsums[threadIdx.x] : 0;
  s[threadIdx.x] = v;
  __syncthreads();
  for (int off = 1; off < 256; off <<= 1) {
    int t = (threadIdx.x >= off) ? s[threadIdx.x - off] : 0;
    __syncthreads();
    s[threadIdx.x] += t;
    __syncthreads();
  }
  if (threadIdx.x < nb) bsums[threadIdx.x] = s[threadIdx.x] - v;  // exclusive
  if (threadIdx.x == 0) rowptr[NN] = NE;
}

__global__ __launch_bounds__(256) void k_scan3(const int* __restrict__ hist,
                                               int* __restrict__ rowptr,
                                               const int* __restrict__ bsums,
                                               float* __restrict__ dinv) {
  int i = blockIdx.x * 256 + threadIdx.x;
  if (i < NN) {
    rowptr[i] += bsums[blockIdx.x];
    dinv[i] = rsqrtf((float)(hist[i] + 1));  // +1 self-loop; deg >= 1 always
  }
}

__global__ __launch_bounds__(256) void k_fill(const int* __restrict__ src,
                                              const int* __restrict__ dst,
                                              const int* __restrict__ rowptr,
                                              int* __restrict__ fill,
                                              int* __restrict__ csr) {
  int e = blockIdx.x * 256 + threadIdx.x;
  if (e < NE) {
    int d = dst[e];
    int p = rowptr[d] + atomicAdd(&fill[d], 1);
    csr[p] = src[e];
  }
}

// ---------------- prep: W (fp32 [k][n]) -> Wt (bf16 [n][k]) ----------------
__global__ __launch_bounds__(256) void k_prep_w(const float* __restrict__ W,
                                                uint16_t* __restrict__ Wt) {
  __shared__ float t[32][33];
  int bx = blockIdx.x & 7, by = blockIdx.x >> 3;
  int tx = threadIdx.x & 31, ty = threadIdx.x >> 5;  // 32 x 8
#pragma unroll
  for (int p = 0; p < 4; ++p)
    t[ty + p * 8][tx] = W[(size_t)(by * 32 + ty + p * 8) * 256 + bx * 32 + tx];
  __syncthreads();
#pragma unroll
  for (int p = 0; p < 4; ++p)
    Wt[(size_t)(bx * 32 + ty + p * 8) * 256 + by * 32 + tx] = f2bf(t[tx][ty + p * 8]);
}

// ---------------- prep: x fp32 -> hi/lo bf16 (exact split) ----------------
__global__ __launch_bounds__(256) void k_split(const float* __restrict__ x,
                                               uint16_t* __restrict__ hi,
                                               uint16_t* __restrict__ lo) {
  size_t i = (size_t)(blockIdx.x * 256 + threadIdx.x) * 4;  // 12.8M floats total
  float4 v = *(const float4*)(x + i);
  float a[4] = {v.x, v.y, v.z, v.w};
  ushort4v h, l;
#pragma unroll
  for (int u = 0; u < 4; ++u) {
    uint16_t hh = f2bf(a[u]);
    h[u] = hh;
    l[u] = f2bf(a[u] - bf2f(hh));
  }
  *(ushort4v*)(hi + i) = h;
  *(ushort4v*)(lo + i) = l;
}

// ---------------- GEMM (m97-style): C(bf16) = dinv * ((Ah [+ Al]) @ Wt^T) ---
// Ah/Al: bf16 [NPAD][256] row-major; Wt: bf16 [256 n][256 k]; C: bf16 [NPAD][256]
// dinv-scaling fused into epilogue: C[row] = bf16(acc[row] * dinv[row]) so the
// aggregation kernel needs no per-edge dinv gather (chain csr->dinv->row cut).
#define BM 128
#define BN 128
#define BK 32

template <int SPLIT>
__global__ __launch_bounds__(256) void k_gemm(const uint16_t* __restrict__ Ah,
                                              const uint16_t* __restrict__ Al,
                                              const uint16_t* __restrict__ Wt,
                                              const float* __restrict__ dinv,
                                              uint16_t* __restrict__ C, int M) {
  __shared__ short Ash[BM * BK];
  __shared__ short Asl[BM * BK];
  __shared__ short Bs[BN * BK];

  const int tid = threadIdx.x;
  const int wave = tid >> 6, lane = tid & 63;
  const int wm = wave >> 1, wn = wave & 1;
  const int m16 = lane & 15, q = lane >> 4;
  const int rowBase = blockIdx.x * BM;
  const int colBase = blockIdx.y * BN;
  const int rsub = lane >> 2;          // 0..15
  const int kch = (lane & 3) * 8;      // bf16-elem offset within BK chunk

  floatx4 acc[4][4];
#pragma unroll
  for (int i = 0; i < 4; ++i)
#pragma unroll
    for (int j = 0; j < 4; ++j) acc[i][j] = (floatx4)(0.0f);

  for (int k0 = 0; k0 < DIM; k0 += BK) {
    __syncthreads();
    // stage: each wave covers 16 rows per pass; lane l -> (row l>>2, 16B chunk l&3)
#pragma unroll
    for (int p = 0; p < 2; ++p) {
      int rb = wave * 16 + p * 64;
      stage16(Ah + (size_t)(rowBase + rb + rsub) * DIM + k0 + kch, &Ash[rb * BK], lane);
      if (SPLIT)
        stage16(Al + (size_t)(rowBase + rb + rsub) * DIM + k0 + kch, &Asl[rb * BK], lane);
      stage16(Wt + (size_t)(colBase + rb + rsub) * DIM + k0 + kch, &Bs[rb * BK], lane);
    }
    __syncthreads();

    short8 ah[4], al[4], b[4];
#pragma unroll
    for (int i = 0; i < 4; ++i) {
      int r = wm * 64 + i * 16 + m16;
      ah[i] = *(const short8*)(&Ash[r * BK + q * 8]);
      if (SPLIT) al[i] = *(const short8*)(&Asl[r * BK + q * 8]);
    }
#pragma unroll
    for (int j = 0; j < 4; ++j) {
      int n = wn * 64 + j * 16 + m16;
      b[j] = *(const short8*)(&Bs[n * BK + q * 8]);
    }
#pragma unroll
    for (int i = 0; i < 4; ++i)
#pragma unroll
      for (int j = 0; j < 4; ++j) {
        if (SPLIT)
          acc[i][j] = __builtin_amdgcn_mfma_f32_16x16x32_bf16(al[i], b[j], acc[i][j], 0, 0, 0);
        acc[i][j] = __builtin_amdgcn_mfma_f32_16x16x32_bf16(ah[i], b[j], acc[i][j], 0, 0, 0);
      }
  }

  // epilogue: C/D layout col = lane&15, row = q*4 + reg  (verified)
#pragma unroll
  for (int i = 0; i < 4; ++i) {
#pragma unroll
    for (int reg = 0; reg < 4; ++reg) {
      int row = rowBase + wm * 64 + i * 16 + q * 4 + reg;
      if (row < M) {
        float dv = dinv[row];
#pragma unroll
        for (int j = 0; j < 4; ++j) {
          int col = colBase + wn * 64 + j * 16 + m16;
          C[(size_t)row * DIM + col] = f2bf(acc[i][j][reg] * dv);
        }
      }
    }
  }
}

// ---------------- Aggregation: paired-edge pull over incoming CSR ----------------
// g is PRE-SCALED: g'[s] = g[s]*dinv[s] (fused into GEMM epilogue).
// lanes 0-31: edge stream A (16B/lane), lanes 32-63: edge stream B.
// Depth-4 unroll per half-wave: 8 g-rows in flight per wave (MLP for latency hiding).
// out[d] = post( dinv[d] * ( sum_s g'[s] + g'[d] ) + b )
template <int FINAL>
__global__ __launch_bounds__(256) void k_agg(const uint16_t* __restrict__ g,
                                             const int* __restrict__ rowptr,
                                             const int* __restrict__ csr,
                                             const float* __restrict__ dinv,
                                             const float* __restrict__ bias,
                                             const float* __restrict__ x,
                                             uint16_t* __restrict__ outb,
                                             float* __restrict__ outf) {
  int d = blockIdx.x * 4 + (threadIdx.x >> 6);
  int lane = threadIdx.x & 63;
  int half = lane >> 5, li = lane & 31;
  int c = li * 8;  // 8 feats (16 B) per lane

  float dd = dinv[d];
  float acc[8];
  {
    ushort8v u = *(const ushort8v*)(g + (size_t)d * DIM + c);
    float wd = half ? 0.f : 1.f;  // self term: g'[d], weight 1 (dd applied at end)
#pragma unroll
    for (int t = 0; t < 8; ++t) acc[t] = bf2f(u[t]) * wd;
  }

  int e = rowptr[d] + half, end = rowptr[d + 1];
  // main loop: 4 edges per half per iter -> 8 edges/wave/iter, 8 rows in flight
  for (; e + 6 < end; e += 8) {
    int s0 = csr[e], s1 = csr[e + 2], s2 = csr[e + 4], s3 = csr[e + 6];
    ushort8v v0 = *(const ushort8v*)(g + (size_t)s0 * DIM + c);
    ushort8v v1 = *(const ushort8v*)(g + (size_t)s1 * DIM + c);
    ushort8v v2 = *(const ushort8v*)(g + (size_t)s2 * DIM + c);
    ushort8v v3 = *(const ushort8v*)(g + (size_t)s3 * DIM + c);
#pragma unroll
    for (int t = 0; t < 8; ++t)
      acc[t] += (bf2f(v0[t]) + bf2f(v1[t])) + (bf2f(v2[t]) + bf2f(v3[t]));
  }
  // remainder: up to 3 edges per half, stride 2
  for (; e < end; e += 2) {
    int s = csr[e];
    ushort8v v = *(const ushort8v*)(g + (size_t)s * DIM + c);
#pragma unroll
    for (int t = 0; t < 8; ++t) acc[t] += bf2f(v[t]);
  }

  // combine halves: lane i += lane i+32
#pragma unroll
  for (int t = 0; t < 8; ++t) acc[t] += __shfl_down(acc[t], 32);

  if (half == 0) {
    float4 b0 = *(const float4*)(bias + c);
    float4 b1 = *(const float4*)(bias + c + 4);
    float bb[8] = {b0.x, b0.y, b0.z, b0.w, b1.x, b1.y, b1.z, b1.w};
    float r[8];
#pragma unroll
    for (int t = 0; t < 8; ++t) r[t] = fmaxf(dd * acc[t] + bb[t], 0.f);
    if (FINAL) {
      float4 x0 = *(const float4*)(x + (size_t)d * DIM + c);
      float4 x1 = *(const float4*)(x + (size_t)d * DIM + c + 4);
      float xx[8] = {x0.x, x0.y, x0.z, x0.w, x1.x, x1.y, x1.z, x1.w};
      float4 o0, o1;
      o0.x = (xx[0] + r[0]) * 0.5f; o0.y = (xx[1] + r[1]) * 0.5f;
      o0.z = (xx[2] + r[2]) * 0.5f; o0.w = (xx[3] + r[3]) * 0.5f;
      o1.x = (xx[4] + r[4]) * 0.5f; o1.y = (xx[5] + r[5]) * 0.5f;
      o1.z = (xx[6] + r[6]) * 0.5f; o1.w = (xx[7] + r[7]) * 0.5f;
      *(float4*)(outf + (size_t)d * DIM + c) = o0;
      *(float4*)(outf + (size_t)d * DIM + c + 4) = o1;
    } else {
      ushort8v o;
#pragma unroll
      for (int t = 0; t < 8; ++t) o[t] = f2bf(r[t]);
      *(ushort8v*)(outb + (size_t)d * DIM + c) = o;
    }
  }
}

// ---------------- launch ----------------
extern "C" void kernel_launch(void* const* d_in, const int* in_sizes, int n_in,
                              void* d_out, int out_size, void* d_ws, size_t ws_size,
                              hipStream_t stream) {
  const float* x  = (const float*)d_in[0];
  const int*   ei = (const int*)d_in[1];   // [2 x NE]: src row, then dst row
  const float* W1 = (const float*)d_in[2];
  const float* b1 = (const float*)d_in[3];
  const float* W2 = (const float*)d_in[4];
  const float* b2 = (const float*)d_in[5];
  float* out = (float*)d_out;

  // workspace layout (all bf16 arrays 16B-aligned)
  int*      hist   = (int*)d_ws;               // NN
  int*      fill   = hist + NN;                // NN
  int*      rowptr = fill + NN;                // NN+1 (padded to 50008)
  int*      bsums  = rowptr + 50008;           // 256
  int*      csr    = bsums + 256;              // NE
  float*    dinv   = (float*)(csr + NE);       // NN
  uint16_t* Wt1    = (uint16_t*)(dinv + NN);   // 256*256
  uint16_t* Wt2    = Wt1 + 256 * 256;          // 256*256
  uint16_t* x_hi   = Wt2 + 256 * 256;          // NPAD*DIM
  uint16_t* x_lo   = x_hi + (size_t)NPAD * DIM;
  uint16_t* g      = x_lo + (size_t)NPAD * DIM;
  uint16_t* h1     = g + (size_t)NPAD * DIM;   // total ~107.0 MB

  const int* esrc = ei;
  const int* edst = ei + NE;

  k_zero<<<(2 * NN + 255) / 256, 256, 0, stream>>>(hist, 2 * NN);
  k_hist<<<(NE + 255) / 256, 256, 0, stream>>>(edst, hist);
  k_scan1<<<196, 256, 0, stream>>>(hist, rowptr, bsums);
  k_scan2<<<1, 256, 0, stream>>>(bsums, rowptr, 196);
  k_scan3<<<196, 256, 0, stream>>>(hist, rowptr, bsums, dinv);
  k_fill<<<(NE + 255) / 256, 256, 0, stream>>>(esrc, edst, rowptr, fill, csr);

  k_prep_w<<<64, 256, 0, stream>>>(W1, Wt1);
  k_prep_w<<<64, 256, 0, stream>>>(W2, Wt2);
  k_split<<<12500, 256, 0, stream>>>(x, x_hi, x_lo);  // 12.8M floats / 4 / 256

  dim3 ggrid((NN + BM - 1) / BM, DIM / BN);
  k_gemm<1><<<ggrid, 256, 0, stream>>>(x_hi, x_lo, Wt1, dinv, g, NN);
  k_agg<0><<<NN / 4, 256, 0, stream>>>(g, rowptr, csr, dinv, b1, nullptr, h1, nullptr);
  k_gemm<0><<<ggrid, 256, 0, stream>>>(h1, nullptr, Wt2, dinv, g, NN);
  k_agg<1><<<NN / 4, 256, 0, stream>>>(g, rowptr, csr, dinv, b2, x, nullptr, out);
}